// Round 4
// baseline (253.505 us; speedup 1.0000x reference)
//
#include <hip/hip_runtime.h>

// TSM (temporal shift): x (128,96,56,56) f32 viewed as (16,8,96,56,56).
//   c in [0,32):  out[b,t] = x[b,t+1]  (zero at t=7)
//   c in [32,64): out[b,t] = x[b,t-1]  (zero at t=0)
//   c in [64,96): out[b,t] = x[b,t]
// Pure plane permutation. Traffic floor: 141.3 MB read + 154.1 MB write.
//
// R6: single-variable A/B vs R5 — NT stores -> plain cached stores.
// Rationale: output (154 MB) fits the 256 MB Infinity Cache (write-back);
// plain stores retire at LLC fill rate and the HBM drain happens after the
// timed kernel window, while the reads (input evicted by the 616 MB poison
// fill) remain forced HBM traffic. NT loads kept: input is strictly
// one-touch, allocating it through L2 was R4's regression (-25%).
// Structure unchanged from R5: 2 adjacent planes per block (even-aligned
// pairs never straddle fold(32,64)/frame(96) boundaries -> uniform block),
// 7 batched NT loads then 7 stores, 6144 blocks, VGPR<64 (32 waves/CU).

#define C_TOT   96
#define FOLD    32
#define NFRAME  8
#define HW4     784        // 56*56/4 float4 per plane
#define PAIR4   1568       // 2 planes of float4
#define NBLOCKS 6144       // 12288 planes / 2

typedef float v4f __attribute__((ext_vector_type(4)));

__global__ __launch_bounds__(256) void tsm_kernel(const v4f* __restrict__ in,
                                                  v4f* __restrict__ out) {
    const int plane0 = blockIdx.x * 2;         // even-aligned pair
    const int c = plane0 % C_TOT;
    const int t = (plane0 / C_TOT) % NFRAME;

    int  delta = 0;                            // block-uniform scalars
    bool zero  = false;
    if (c < FOLD)          { delta =  C_TOT; zero = (t == NFRAME - 1); }
    else if (c < 2 * FOLD) { delta = -C_TOT; zero = (t == 0); }

    const long base = (long)plane0 * HW4;
    const int  j    = threadIdx.x;
    v4f* __restrict__ o = out + base + j;
    const bool tail = (j < PAIR4 - 1536);      // 32 lanes

    if (zero) {
        const v4f z = (v4f){0.f, 0.f, 0.f, 0.f};
        o[0 * 256] = z;
        o[1 * 256] = z;
        o[2 * 256] = z;
        o[3 * 256] = z;
        o[4 * 256] = z;
        o[5 * 256] = z;
        if (tail) o[1536] = z;
    } else {
        const v4f* __restrict__ s = in + base + (long)delta * HW4 + j;
        const v4f a0 = __builtin_nontemporal_load(&s[0 * 256]);
        const v4f a1 = __builtin_nontemporal_load(&s[1 * 256]);
        const v4f a2 = __builtin_nontemporal_load(&s[2 * 256]);
        const v4f a3 = __builtin_nontemporal_load(&s[3 * 256]);
        const v4f a4 = __builtin_nontemporal_load(&s[4 * 256]);
        const v4f a5 = __builtin_nontemporal_load(&s[5 * 256]);
        v4f a6;
        if (tail) a6 = __builtin_nontemporal_load(&s[1536]);
        o[0 * 256] = a0;
        o[1 * 256] = a1;
        o[2 * 256] = a2;
        o[3 * 256] = a3;
        o[4 * 256] = a4;
        o[5 * 256] = a5;
        if (tail) o[1536] = a6;
    }
}

extern "C" void kernel_launch(void* const* d_in, const int* in_sizes, int n_in,
                              void* d_out, int out_size, void* d_ws, size_t ws_size,
                              hipStream_t stream) {
    const v4f* x   = (const v4f*)d_in[0];
    v4f*       out = (v4f*)d_out;
    tsm_kernel<<<NBLOCKS, 256, 0, stream>>>(x, out);
}

// Round 5
// 246.222 us; speedup vs baseline: 1.0296x; 1.0296x over previous
//
#include <hip/hip_runtime.h>

// TSM (temporal shift): x (128,96,56,56) f32 viewed as (16,8,96,56,56).
//   c in [0,32):  out[b,t] = x[b,t+1]  (zero at t=7)
//   c in [32,64): out[b,t] = x[b,t-1]  (zero at t=0)
//   c in [64,96): out[b,t] = x[b,t]
// Pure plane permutation; one block per 56x56 plane (784 float4 = 12544 B).
//
// R7 = R0 restored (best measured: 245.9 us). Full A/B matrix conclusion:
//   loads:  NT >> cached (+25% for cached — one-touch stream, L2 allocation
//           of 141 MB dead data; R3/R4)
//   stores: NT > cached  (+5 us for cached — write-back drain stays inside
//           the kernel window, LLC does NOT defer it; R6)
//   geometry: 1 plane/block ~= 2 planes/block (R5, within fill variance)
//             >> big chunks (R3)
//   batch depth 4 vs 7 outstanding loads: no measurable difference.
// Kernel ~58 us for 295 MB logical traffic = 5.1 TB/s = 81% of m13's
// 6.29 TB/s D2D copy ceiling; measured total is dominated by ~188 us of
// fixed harness poison-fill dispatches (2 x ~94 us at 6.6 TB/s).

#define C_TOT   96
#define FOLD    32
#define NFRAME  8
#define HW4     784   // 56*56/4 float4 per plane
#define NPLANES 12288 // 128*96

typedef float v4f __attribute__((ext_vector_type(4)));

__global__ __launch_bounds__(256) void tsm_kernel(const v4f* __restrict__ in,
                                                  v4f* __restrict__ out) {
    const int plane = blockIdx.x;              // b*768 + t*96 + c
    const int c = plane % C_TOT;
    const int t = (plane / C_TOT) % NFRAME;

    int  delta = 0;                            // block-uniform scalars
    bool zero  = false;
    if (c < FOLD)          { delta =  C_TOT; zero = (t == NFRAME - 1); }
    else if (c < 2 * FOLD) { delta = -C_TOT; zero = (t == 0); }

    const long base = (long)plane * HW4;
    v4f* o = out + base;
    const int j = threadIdx.x;                 // 784 = 3*256 + 16

    if (zero) {
        const v4f z = (v4f){0.f, 0.f, 0.f, 0.f};
        __builtin_nontemporal_store(z, &o[j]);
        __builtin_nontemporal_store(z, &o[j + 256]);
        __builtin_nontemporal_store(z, &o[j + 512]);
        if (j < HW4 - 768) __builtin_nontemporal_store(z, &o[j + 768]);
    } else {
        const v4f* s = in + base + (long)delta * HW4;
        v4f a0 = __builtin_nontemporal_load(&s[j]);
        v4f a1 = __builtin_nontemporal_load(&s[j + 256]);
        v4f a2 = __builtin_nontemporal_load(&s[j + 512]);
        v4f a3;
        const bool tail = (j < HW4 - 768);
        if (tail) a3 = __builtin_nontemporal_load(&s[j + 768]);
        __builtin_nontemporal_store(a0, &o[j]);
        __builtin_nontemporal_store(a1, &o[j + 256]);
        __builtin_nontemporal_store(a2, &o[j + 512]);
        if (tail) __builtin_nontemporal_store(a3, &o[j + 768]);
    }
}

extern "C" void kernel_launch(void* const* d_in, const int* in_sizes, int n_in,
                              void* d_out, int out_size, void* d_ws, size_t ws_size,
                              hipStream_t stream) {
    const v4f* x   = (const v4f*)d_in[0];
    v4f*       out = (v4f*)d_out;
    tsm_kernel<<<NPLANES, 256, 0, stream>>>(x, out);
}